// Round 6
// baseline (2252.379 us; speedup 1.0000x reference)
//
#include <hip/hip_runtime.h>

#define VV 32000
#define EE 256
#define HH 512
#define BB 32
#define SS 80
#define TT 80
// decoder rows = B*(T-1) = 2528, padded to 2560 (20 tiles of 128)

typedef __attribute__((ext_vector_type(8))) _Float16 half8;
typedef __attribute__((ext_vector_type(4))) _Float16 half4;
typedef __attribute__((ext_vector_type(4))) float floatx4;
typedef unsigned long long u64;

#define SENT 0xFFFFFFFFFFFFFFFFull   // 4x fp16 NaN: unreachable for finite GRU h

__device__ __forceinline__ void gload16(const _Float16* g, _Float16* l) {
  __builtin_amdgcn_global_load_lds((const __attribute__((address_space(1))) void*)g,
                                   (__attribute__((address_space(3))) void*)l, 16, 0, 0);
}

__device__ __forceinline__ u64 aload(const u64* p) {
  return __hip_atomic_load(p, __ATOMIC_RELAXED, __HIP_MEMORY_SCOPE_AGENT);
}
__device__ __forceinline__ void astore(u64* p, u64 v) {
  __hip_atomic_store(p, v, __ATOMIC_RELAXED, __HIP_MEMORY_SCOPE_AGENT);
}

__device__ __forceinline__ float dot8(half8 a, half8 b, float c) {
  typedef __attribute__((ext_vector_type(2))) _Float16 half2v;
  half2v a0 = {a[0],a[1]}, a1 = {a[2],a[3]}, a2 = {a[4],a[5]}, a3 = {a[6],a[7]};
  half2v b0 = {b[0],b[1]}, b1 = {b[2],b[3]}, b2 = {b[4],b[5]}, b3 = {b[6],b[7]};
  c = __builtin_amdgcn_fdot2(a0, b0, c, false);
  c = __builtin_amdgcn_fdot2(a1, b1, c, false);
  c = __builtin_amdgcn_fdot2(a2, b2, c, false);
  c = __builtin_amdgcn_fdot2(a3, b3, c, false);
  return c;
}

__device__ __forceinline__ float sigm(float x) { return 1.f/(1.f + __expf(-x)); }
__device__ __forceinline__ float tanh_f(float x) { return 2.f/(1.f + __expf(-2.f*x)) - 1.f; }

// ---------------- embedding gather (fp32 -> fp16 rows) ----------------
__global__ __launch_bounds__(256) void embed_gather(
    const int* __restrict__ src, const int* __restrict__ tgt,
    const float* __restrict__ emb,
    _Float16* __restrict__ xsrc, _Float16* __restrict__ xdec)
{
  const int r = blockIdx.x;
  const int e = threadIdx.x; // EE == 256
  if (r < 2560) {
    const int tok = src[r];
    xsrc[(size_t)r*EE + e] = (_Float16)emb[(size_t)tok*EE + e];
  } else {
    const int rr = r - 2560;
    if (rr < 2528) {
      const int b = rr / 79, t = rr - b*79;
      const int tok = tgt[b*TT + t];
      xdec[(size_t)rr*EE + e] = (_Float16)emb[(size_t)tok*EE + e];
    } else {
      xdec[(size_t)rr*EE + e] = (_Float16)0.f;
    }
  }
}

// ---------------- weight fp32 -> fp16 conversion (Wih, out_W) ----------------
__global__ __launch_bounds__(256) void wconv(
    const float* __restrict__ we, const float* __restrict__ wd, const float* __restrict__ ow,
    _Float16* __restrict__ weh, _Float16* __restrict__ wdh, _Float16* __restrict__ owh)
{
  const long n1 = 1536L*256;
  const long total = 2*n1 + (long)VV*1024;
  for (long i = (long)blockIdx.x*256 + threadIdx.x; i < total; i += (long)gridDim.x*256) {
    if (i < n1)           weh[i]        = (_Float16)we[i];
    else if (i < 2*n1)    wdh[i-n1]     = (_Float16)wd[i-n1];
    else                  owh[i-2*n1]   = (_Float16)ow[i-2*n1];
  }
}

// ---------------- generic fp16 MFMA GEMM: C(MxN) = A(MxK) * B(NxK)^T + bias ----
// MODE 0: C[row*ldc+col].
// MODE 1: logits scatter: row<2528 -> [b,t+1,:]; pad row 2528+b -> [b,0,:] = 0.
template<int MODE>
__global__ __launch_bounds__(256) void mfma_gemm(
    const _Float16* __restrict__ A, int lda,
    const _Float16* __restrict__ Bm, int ldb,
    const float* __restrict__ bias,
    float* __restrict__ Cout, int ldc, int K)
{
  __shared__ _Float16 As[4096];  // 128 x 32
  __shared__ _Float16 Bs[4096];  // 128 x 32
  const int tid = threadIdx.x;
  const int lane = tid & 63;
  const int wv = tid >> 6;
  const int wr = wv >> 1, wc = wv & 1;
  const int mt = blockIdx.y, nt = blockIdx.x;
  floatx4 acc[4][4];
#pragma unroll
  for (int i=0;i<4;++i)
#pragma unroll
    for (int j=0;j<4;++j) acc[i][j] = (floatx4){0.f,0.f,0.f,0.f};
  const int srow = lane >> 2;
  const int scol = (lane & 3) * 8;
  const _Float16* Ab = A + (size_t)(mt*128)*lda;
  const _Float16* Bb = Bm + (size_t)(nt*128)*ldb;
  const int g8 = (lane >> 4) * 8;
  const int lr = lane & 15;
  for (int kb = 0; kb < K; kb += 32) {
    __syncthreads();
#pragma unroll
    for (int cc = 0; cc < 2; ++cc) {
      const int c = wv*2 + cc;
      gload16(Ab + (size_t)(c*16 + srow)*lda + kb + scol, As + c*512);
      gload16(Bb + (size_t)(c*16 + srow)*ldb + kb + scol, Bs + c*512);
    }
    __syncthreads();
    half8 af[4], bf[4];
#pragma unroll
    for (int i=0;i<4;++i) af[i] = *(const half8*)(As + (wr*64 + i*16 + lr)*32 + g8);
#pragma unroll
    for (int j=0;j<4;++j) bf[j] = *(const half8*)(Bs + (wc*64 + j*16 + lr)*32 + g8);
#pragma unroll
    for (int i=0;i<4;++i)
#pragma unroll
      for (int j=0;j<4;++j)
        acc[i][j] = __builtin_amdgcn_mfma_f32_16x16x32_f16(af[i], bf[j], acc[i][j], 0,0,0);
  }
  const int rm = 4*(lane>>4);
#pragma unroll
  for (int i=0;i<4;++i) {
#pragma unroll
    for (int r=0;r<4;++r) {
      const int row = mt*128 + wr*64 + i*16 + rm + r;
#pragma unroll
      for (int j=0;j<4;++j) {
        const int col = nt*128 + wc*64 + j*16 + lr;
        const float v = acc[i][j][r] + bias[col];
        if (MODE == 0) {
          Cout[(size_t)row*ldc + col] = v;
        } else {
          if (row < 2528) {
            const int b = row / 79;
            const int t = row - b*79;
            Cout[(size_t)(b*80 + t + 1)*VV + col] = v;
          } else {
            Cout[(size_t)((row - 2528)*80)*VV + col] = 0.f;  // logits[b,0,:]=0
          }
        }
      }
    }
  }
}

// ---------------- fused recurrence: weight-stationary, DATA-POLL protocol ----
// 32 WGs x 128 threads. WG w owns h cols [w*16,w*16+16); Whh slice in LDS.
// h exchange: ring of 4 buffers; words tagged implicitly -- 0xFFFF... (fp16
// NaN x4) is the "empty" sentinel, unreachable for finite GRU h. Consumers
// burst-load all 32 words and retry only sentinel words: detection == data
// (2 LLC hops/step). Each thread re-poisons the word it owns in buffer
// (k+2)&3 after the consume barrier; the per-wave s_waitcnt vmcnt(0) before
// the data store orders poison < data globally (ring-depth-4 induction makes
// stale reads impossible). No flags, no publish barrier, no s_sleep.
#define SEQ_SMEM ((48*520 + 80*512 + 512)*2 + 160*4)
__global__ __launch_bounds__(128) void seq_fused(
    const float* __restrict__ eWhh, const float* __restrict__ dWhh,
    const float* __restrict__ ebhh, const float* __restrict__ dbhh,
    const float* __restrict__ giE, const float* __restrict__ giD,
    _Float16* __restrict__ h16,    // ring 4 x 32 x 512 fp16 (B0-2 poisoned, B3 zeros)
    _Float16* __restrict__ comb)
{
  extern __shared__ char smem[];
  _Float16* whh  = (_Float16*)smem;        // [48][520] fp16 (padded rows)
  _Float16* eo_l = whh + 48*520;           // [80][512] fp16
  _Float16* hsh  = eo_l + 80*512;          // [512]
  float* sc = (float*)(hsh + 512);         // [80]
  float* aw = sc + 80;                     // [80]

  const int w = blockIdx.x;
  const int tid = threadIdx.x;
  const int lane = tid & 63;
  const int wv = tid >> 6;            // 0..1 batch group
  const int lr = lane & 15;
  const int l4 = lane >> 4;           // 0..3
  const int b  = wv*16 + lr;          // batch this thread covers
  const int jc = w*16 + 4*l4;         // global h-col base (4 wide)

  auto ring = [&](int x){ return (u64*)h16 + (size_t)(x & 3)*(BB*HH/4); };

  auto loadW = [&](const float* W){
    for (int i = tid; i < 48*512; i += 128) {
      const int r = i >> 9, k = i & 511;
      whh[r*520 + k] = (_Float16)W[((size_t)(r>>4)*512 + w*16 + (r&15))*512 + k];
    }
  };

  // bias registers (fp32, 4 cols each gate)
  const floatx4 ebr = *(const floatx4*)&ebhh[jc];
  const floatx4 ebz = *(const floatx4*)&ebhh[HH + jc];
  const floatx4 ebn = *(const floatx4*)&ebhh[2*HH + jc];
  const floatx4 dbr = *(const floatx4*)&dbhh[jc];
  const floatx4 dbz = *(const floatx4*)&dbhh[HH + jc];
  const floatx4 dbn = *(const floatx4*)&dbhh[2*HH + jc];

  float hp[4] = {0.f, 0.f, 0.f, 0.f};   // own fp32 h_prev (batch b, cols jc..jc+3)

  // one recurrence step: consume bufR (poll), poison own word in bufP,
  // MFMA + gates, publish own word to bufW, optional stash of row w -> LDS.
  auto gru = [&](const float* girow, floatx4 bR, floatx4 bZ, floatx4 bN,
                 const u64* bufR, u64* bufW, u64* bufP, _Float16* stash){
    const floatx4 gr = *(const floatx4*)(girow);
    const floatx4 gz = *(const floatx4*)(girow + HH);
    const floatx4 gn = *(const floatx4*)(girow + 2*HH);
    const u64* hb = bufR + b*128 + l4*2;
    u64 hq[32];
#pragma unroll
    for (int kt = 0; kt < 16; ++kt) {
      hq[2*kt]   = aload(hb + kt*8);
      hq[2*kt+1] = aload(hb + kt*8 + 1);
    }
    for (;;) {                        // retry only sentinel words
      bool again = false;
#pragma unroll
      for (int i = 0; i < 32; ++i) {
        if (hq[i] == SENT) {
          hq[i] = aload(hb + (i>>1)*8 + (i&1));
          again |= (hq[i] == SENT);
        }
      }
      if (!again) break;
    }
    __syncthreads();                  // whole WG verified h(k-1) present
    astore(bufP + b*128 + w*4 + l4, SENT);   // re-poison own word for step k+2
    u64 sq = 0;
    if (stash) sq = aload(bufR + w*128 + tid);  // row w (verified complete)
    floatx4 a0 = (floatx4){0.f,0.f,0.f,0.f}, a1 = a0, a2 = a0;
#pragma unroll
    for (int kt = 0; kt < 16; ++kt) {
      union { u64 q[2]; half8 v; } hu;
      hu.q[0] = hq[2*kt]; hu.q[1] = hq[2*kt+1];
      const int ko = kt*32 + l4*8;
      const half8 x0 = *(const half8*)&whh[(     lr)*520 + ko];
      const half8 x1 = *(const half8*)&whh[(16 + lr)*520 + ko];
      const half8 x2 = *(const half8*)&whh[(32 + lr)*520 + ko];
      a0 = __builtin_amdgcn_mfma_f32_16x16x32_f16(x0, hu.v, a0, 0,0,0);
      a1 = __builtin_amdgcn_mfma_f32_16x16x32_f16(x1, hu.v, a1, 0,0,0);
      a2 = __builtin_amdgcn_mfma_f32_16x16x32_f16(x2, hu.v, a2, 0,0,0);
    }
    union { u64 q; _Float16 h[4]; } hw;
#pragma unroll
    for (int r = 0; r < 4; ++r) {
      const float rg = sigm(gr[r] + a0[r] + bR[r]);
      const float zg = sigm(gz[r] + a1[r] + bZ[r]);
      const float ng = tanh_f(gn[r] + rg*(a2[r] + bN[r]));
      const float hn = (1.f - zg)*ng + zg*hp[r];
      hp[r] = hn;
      hw.h[r] = (_Float16)hn;
    }
    asm volatile("s_waitcnt vmcnt(0)" ::: "memory");  // poison (+reads) drained
    astore(bufW + b*128 + w*4 + l4, hw.q);            // publish: word valid now
    if (stash) *(u64*)&stash[tid*4] = sq;
  };

  auto attention = [&](int trow){
    const half8 hf = *(const half8*)&hsh[lane*8];
#pragma unroll 4
    for (int i = 0; i < 40; ++i) {
      const int s = wv*40 + i;
      const half8 ev = *(const half8*)&eo_l[s*512 + lane*8];
      float pt = dot8(ev, hf, 0.f);
#pragma unroll
      for (int o = 32; o; o >>= 1) pt += __shfl_xor(pt, o);
      if (lane == 0) sc[s] = pt;
    }
    __syncthreads();
    if (wv == 0) {   // softmax over 80 (wave 0)
      const float v0 = sc[lane];
      const float v1 = (lane < 16) ? sc[64+lane] : -1e30f;
      float m = fmaxf(v0, v1);
#pragma unroll
      for (int o = 32; o; o >>= 1) m = fmaxf(m, __shfl_xor(m, o));
      const float e0 = __expf(v0 - m);
      const float e1 = (lane < 16) ? __expf(v1 - m) : 0.f;
      float ssum = e0 + e1;
#pragma unroll
      for (int o = 32; o; o >>= 1) ssum += __shfl_xor(ssum, o);
      const float inv = 1.f/ssum;
      aw[lane] = e0*inv;
      if (lane < 16) aw[64+lane] = e1*inv;
    }
    __syncthreads();
    float c0=0.f, c1=0.f, c2=0.f, c3=0.f;
#pragma unroll 8
    for (int s = 0; s < SS; ++s) {
      const float a = aw[s];
      const half4 hv = *(const half4*)&eo_l[s*512 + tid*4];
      c0 += a*(float)hv[0]; c1 += a*(float)hv[1];
      c2 += a*(float)hv[2]; c3 += a*(float)hv[3];
    }
    _Float16* cr = comb + ((size_t)w*79 + trow)*1024;
    *(u64*)&cr[tid*4] = *(const u64*)&hsh[tid*4];
    union { u64 q; _Float16 h[4]; } cu;
    cu.h[0]=(_Float16)c0; cu.h[1]=(_Float16)c1; cu.h[2]=(_Float16)c2; cu.h[3]=(_Float16)c3;
    *(u64*)&cr[512 + tid*4] = cu.q;
  };

  loadW(eWhh);
  __syncthreads();

  // -------- encoder: k = 0..79 (h(-1)=zeros in B3; B0-2 pre-poisoned) -------
  for (int k = 0; k < SS; ++k) {
    gru(giE + (size_t)(b*SS + k)*1536 + jc, ebr, ebz, ebn,
        ring(k+3), ring(k), ring(k+2),
        (k > 0) ? (eo_l + (k-1)*512) : nullptr);
  }

  // -------- decoder: k = 80..158 (t = k-80) --------
  __syncthreads();     // all own MFMA reads of enc whh done
  loadW(dWhh);
  __syncthreads();
  for (int t = 0; t < TT-1; ++t) {
    const int k = 80 + t;
    gru(giD + (size_t)(b*79 + t)*1536 + jc, dbr, dbz, dbn,
        ring(k+3), ring(k), ring(k+2),
        (t == 0) ? (eo_l + 79*512) : hsh);   // t=0: enc h(79); else h(t-1)
    if (t > 0) { __syncthreads(); attention(t-1); }
  }
  // final: attention(78) on h(158) (buffer 158&3 == 2)
  {
    const u64* bufR = ring(158);
    u64 q = aload(bufR + w*128 + tid);
    while (q == SENT) q = aload(bufR + w*128 + tid);
    *(u64*)&hsh[tid*4] = q;
  }
  __syncthreads();
  attention(TT-2);
}

extern "C" void kernel_launch(void* const* d_in, const int* in_sizes, int n_in,
                              void* d_out, int out_size, void* d_ws, size_t ws_size,
                              hipStream_t stream) {
  (void)in_sizes; (void)n_in; (void)out_size; (void)ws_size;
  const int*   src  = (const int*)d_in[0];
  const int*   tgt  = (const int*)d_in[1];
  const float* emb  = (const float*)d_in[2];
  const float* eWih = (const float*)d_in[3];
  const float* eWhh = (const float*)d_in[4];
  const float* ebih = (const float*)d_in[5];
  const float* ebhh = (const float*)d_in[6];
  const float* dWih = (const float*)d_in[7];
  const float* dWhh = (const float*)d_in[8];
  const float* dbih = (const float*)d_in[9];
  const float* dbhh = (const float*)d_in[10];
  const float* outW = (const float*)d_in[11];
  const float* outb = (const float*)d_in[12];
  float* out = (float*)d_out;

  char* p = (char*)d_ws;
  auto alloc = [&](size_t n){ char* r = p; p += (n + 255) & ~(size_t)255; return r; };
  _Float16* xsrc = (_Float16*)alloc((size_t)2560*256*2);
  _Float16* xdec = (_Float16*)alloc((size_t)2560*256*2);
  _Float16* wEh  = (_Float16*)alloc((size_t)1536*256*2);
  _Float16* wDh  = (_Float16*)alloc((size_t)1536*256*2);
  _Float16* oWh  = (_Float16*)alloc((size_t)VV*1024*2);
  float*    giE  = (float*)alloc((size_t)2560*1536*4);
  float*    giD  = (float*)alloc((size_t)2560*1536*4);
  _Float16* h16  = (_Float16*)alloc((size_t)4*BB*HH*2);   // ring of 4
  _Float16* comb = (_Float16*)alloc((size_t)2560*1024*2);

  // ring init: B0..B2 poisoned (0xFFFF.. sentinel), B3 = h(-1) = zeros
  hipMemsetAsync(h16, 0xFF, (size_t)3*BB*HH*2, stream);
  hipMemsetAsync(h16 + (size_t)3*BB*HH, 0, (size_t)BB*HH*2, stream);

  embed_gather<<<5120, 256, 0, stream>>>(src, tgt, emb, xsrc, xdec);
  wconv<<<2048, 256, 0, stream>>>(eWih, dWih, outW, wEh, wDh, oWh);
  mfma_gemm<0><<<dim3(12,20), 256, 0, stream>>>(xsrc, 256, wEh, 256, ebih, giE, 1536, 256);
  mfma_gemm<0><<<dim3(12,20), 256, 0, stream>>>(xdec, 256, wDh, 256, dbih, giD, 1536, 256);
  hipFuncSetAttribute((const void*)seq_fused,
                      hipFuncAttributeMaxDynamicSharedMemorySize, SEQ_SMEM);
  seq_fused<<<32, 128, SEQ_SMEM, stream>>>(eWhh, dWhh, ebhh, dbhh, giE, giD,
                                           h16, comb);
  mfma_gemm<1><<<dim3(250,20), 256, 0, stream>>>(comb, 1024, oWh, 1024, outb, out, 0, 1024);
}